// Round 9
// baseline (183.862 us; speedup 1.0000x reference)
//
#include <hip/hip_runtime.h>
#include <math.h>

#define NB   8
#define CIN  256
#define CMID 16
#define NH   128
#define NW   128
#define HWSZ 16384
#define HW4  4096
#define NANG 8
#define NRAD 9

typedef float    f32x4_t __attribute__((ext_vector_type(4)));
typedef unsigned u32x2_t __attribute__((ext_vector_type(2)));

__device__ __forceinline__ unsigned short f2bf(float f) {
    unsigned u = __float_as_uint(f);
    u += 0x7fffu + ((u >> 16) & 1u);          // round-to-nearest-even
    return (unsigned short)(u >> 16);
}
__device__ __forceinline__ float bf_lo(unsigned u) { return __uint_as_float(u << 16); }
__device__ __forceinline__ float bf_hi(unsigned u) { return __uint_as_float(u & 0xffff0000u); }
__device__ __forceinline__ unsigned pack2(float a, float b) {
    return (unsigned)f2bf(a) | ((unsigned)f2bf(b) << 16);
}
__device__ __forceinline__ ushort4 pack4(f32x4_t v) {
    return make_ushort4(f2bf(v.x), f2bf(v.y), f2bf(v.z), f2bf(v.w));
}
__device__ __forceinline__ f32x4_t unpack4(ushort4 u) {
    return (f32x4_t){ __uint_as_float((unsigned)u.x << 16),
                      __uint_as_float((unsigned)u.y << 16),
                      __uint_as_float((unsigned)u.z << 16),
                      __uint_as_float((unsigned)u.w << 16) };
}

__device__ __forceinline__ int bitrev7(int v) {
    return (int)(__brev((unsigned)v) >> 25);
}

// Gain in bit-reversed (both dims), ifftshift-folded order, pre-scaled by 1/16384.
__global__ void __launch_bounds__(256) gain_kernel(const float* __restrict__ fw,
                                                   float* __restrict__ gain) {
    int p  = blockIdx.x * 256 + threadIdx.x;
    int py = p >> 7, px = p & 127;
    int fy = bitrev7(py), fx = bitrev7(px);
    int hy = (fy + 64) & 127, hx = (fx + 64) & 127;
    float dy = (float)(hy - 64), dx = (float)(hx - 64);
    float r = sqrtf(dy * dy + dx * dx);
    int ridx = (int)floorf(r * 0.125f);
    if (ridx > NRAD - 1) ridx = NRAD - 1;
    const float PI_F = 3.14159265358979323846f;
    float theta = fmodf(atan2f(dy, dx) + PI_F, PI_F);
    const float delta = (float)(M_PI / 8.0);
    const float hwid  = (float)(1.5 * (M_PI / 8.0) / 2.0);
    float wv[NANG];
    float wsum = 0.f;
#pragma unroll
    for (int a = 0; a < NANG; ++a) {
        float c = ((float)a + 0.5f) * delta;
        float dist = fabsf(theta - c);
        float wa = fmaxf(1.0f - dist / hwid, 0.0f);
        if (!(dist < hwid)) wa = 0.0f;
        wv[a] = wa;
        wsum += wa;
    }
    float inv = 1.0f / (wsum + 1e-8f);
#pragma unroll
    for (int m = 0; m < CMID; ++m) {
        float g = 0.f;
#pragma unroll
        for (int a = 0; a < NANG; ++a)
            g += wv[a] * fw[(m * NANG + a) * NRAD + ridx];
        gain[m * HWSZ + p] = g * inv * (1.0f / 16384.0f);
    }
}

// K2 (fused proj + row-FFT): block = (2-row strip, b), 512 threads = 8 warps.
// Warp w accumulates channels [32w,32w+32) for all 64 float4 positions of the
// strip; two-stage bf16 LDS reduce (in-place aliased with FFT buffer); then
// 32 x 128-pt row-DIF FFT; writes packed bf16-complex xf.
__global__ void __launch_bounds__(512, 4) proj_fft(const float* __restrict__ x,
                                                   const float* __restrict__ w_in,
                                                   unsigned* __restrict__ xf) {
    __shared__ ushort4 red[CMID][4][64];          // 32 KB; aliased as fftbuf[m][256]
    float2* fftbuf = (float2*)red;
    int b = blockIdx.y, strip = blockIdx.x;       // strip in [0,64)
    int t = threadIdx.x;
    int w = t >> 6, l = t & 63;

    // ---- accumulate 32 channels per warp, float4 lanes, 8-deep bursts ----
    const f32x4_t* xb = (const f32x4_t*)(x + (size_t)b * CIN * HWSZ) + strip * 64 + l;
    f32x4_t facc[CMID];
#pragma unroll
    for (int m = 0; m < CMID; ++m) facc[m] = (f32x4_t){0.f, 0.f, 0.f, 0.f};
    int c0 = w * 32;
    for (int c = c0; c < c0 + 32; c += 8) {
        f32x4_t v[8];
#pragma unroll
        for (int k = 0; k < 8; ++k)
            v[k] = xb[(size_t)(c + k) * HW4];
#pragma unroll
        for (int k = 0; k < 8; ++k) {
#pragma unroll
            for (int m = 0; m < CMID; ++m)
                facc[m] += w_in[m * CIN + c + k] * v[k];
        }
    }
    // ---- stage 1: warps 4-7 park partials; warps 0-3 absorb ----
    if (w >= 4) {
#pragma unroll
        for (int m = 0; m < CMID; ++m) red[m][w - 4][l] = pack4(facc[m]);
    }
    __syncthreads();
    if (w < 4) {
#pragma unroll
        for (int m = 0; m < CMID; ++m) {
            facc[m] += unpack4(red[m][w][l]);
            red[m][w][l] = pack4(facc[m]);        // same addr this thread read
        }
    }
    __syncthreads();
    // ---- stage 2: warp w owns m in {2w, 2w+1}; read 4 contributions ----
    ushort4 c4[2][4];
#pragma unroll
    for (int mm = 0; mm < 2; ++mm)
#pragma unroll
        for (int k = 0; k < 4; ++k)
            c4[mm][k] = red[2 * w + mm][k][l];
    __syncthreads();                              // all reads before aliased writes
#pragma unroll
    for (int mm = 0; mm < 2; ++mm) {
        int m = 2 * w + mm;
        f32x4_t s = unpack4(c4[mm][0]) + unpack4(c4[mm][1]) +
                    unpack4(c4[mm][2]) + unpack4(c4[mm][3]);
        fftbuf[m * 256 + 4 * l + 0] = make_float2(s.x, 0.f);
        fftbuf[m * 256 + 4 * l + 1] = make_float2(s.y, 0.f);
        fftbuf[m * 256 + 4 * l + 2] = make_float2(s.z, 0.f);
        fftbuf[m * 256 + 4 * l + 3] = make_float2(s.w, 0.f);
    }
    __syncthreads();
    // ---- 32 x 128-pt forward row-DIF FFT (rows flat at fftbuf + f*128) ----
    const float PI_F = 3.14159265358979323846f;
    int j = l;
    for (int ls = 6; ls >= 0; --ls) {
        int s = 1 << ls;
        int off = j & (s - 1);
        int i0 = ((j >> ls) << (ls + 1)) + off;
        float ang = -PI_F * (float)off / (float)s;
        float sn, cs;
        __sincosf(ang, &sn, &cs);
        for (int f = w; f < 32; f += 8) {
            float2* row = fftbuf + f * 128;
            float2 a = row[i0];
            float2 bb = row[i0 + s];
            row[i0] = make_float2(a.x + bb.x, a.y + bb.y);
            float dx_ = a.x - bb.x, dy_ = a.y - bb.y;
            row[i0 + s] = make_float2(dx_ * cs - dy_ * sn, dx_ * sn + dy_ * cs);
        }
        __syncthreads();
    }
    // ---- write packed bf16-complex xf ----
    unsigned* xo = xf + (size_t)(b * CMID) * HWSZ + strip * 256;
    for (int i = t; i < CMID * 256; i += 512) {
        int m = i >> 8, px = i & 255;
        xo[(size_t)m * HWSZ + px] = pack2(fftbuf[i].x, fftbuf[i].y);
    }
}

// K4: forward col-DIF + gain + inverse col-DIT on bf16-complex xf (in place).
__global__ void __launch_bounds__(256) fft_cols_gain(unsigned* __restrict__ xf,
                                                     const float* __restrict__ gain) {
    __shared__ float2 buf[128 * 33];
    int img = blockIdx.y;
    int m   = img & (CMID - 1);
    int c0  = blockIdx.x * 32;
    int t   = threadIdx.x;
    unsigned* xi = xf + (size_t)img * HWSZ;

    for (int idx = t; idx < 128 * 32; idx += 256) {
        int r = idx >> 5, lc = idx & 31;
        unsigned u = xi[r * NW + c0 + lc];
        buf[r * 33 + lc] = make_float2(bf_lo(u), bf_hi(u));
    }
    __syncthreads();
    const float PI_F = 3.14159265358979323846f;
    int lc = t & 31;
    int jb = t >> 5;
    for (int ls = 6; ls >= 0; --ls) {
        int s = 1 << ls;
        for (int j = jb; j < 64; j += 8) {
            int off = j & (s - 1);
            int i0 = ((j >> ls) << (ls + 1)) + off;
            float ang = -PI_F * (float)off / (float)s;
            float sn, cs;
            __sincosf(ang, &sn, &cs);
            float2 a = buf[i0 * 33 + lc];
            float2 bb = buf[(i0 + s) * 33 + lc];
            buf[i0 * 33 + lc] = make_float2(a.x + bb.x, a.y + bb.y);
            float dx_ = a.x - bb.x, dy_ = a.y - bb.y;
            buf[(i0 + s) * 33 + lc] = make_float2(dx_ * cs - dy_ * sn, dx_ * sn + dy_ * cs);
        }
        __syncthreads();
    }
    {
        const float* gm = gain + (size_t)m * HWSZ;
        for (int idx = t; idx < 128 * 32; idx += 256) {
            int r = idx >> 5, lcc = idx & 31;
            float g = gm[r * NW + c0 + lcc];
            buf[r * 33 + lcc].x *= g;
            buf[r * 33 + lcc].y *= g;
        }
        __syncthreads();
    }
    for (int ls = 0; ls <= 6; ++ls) {
        int s = 1 << ls;
        for (int j = jb; j < 64; j += 8) {
            int off = j & (s - 1);
            int i0 = ((j >> ls) << (ls + 1)) + off;
            float ang = PI_F * (float)off / (float)s;
            float sn, cs;
            __sincosf(ang, &sn, &cs);
            float2 a = buf[i0 * 33 + lc];
            float2 bb = buf[(i0 + s) * 33 + lc];
            float tx = bb.x * cs - bb.y * sn, ty = bb.x * sn + bb.y * cs;
            buf[i0 * 33 + lc] = make_float2(a.x + tx, a.y + ty);
            buf[(i0 + s) * 33 + lc] = make_float2(a.x - tx, a.y - ty);
        }
        __syncthreads();
    }
    for (int idx = t; idx < 128 * 32; idx += 256) {
        int r = idx >> 5, lcc = idx & 31;
        xi[r * NW + c0 + lcc] = pack2(buf[r * 33 + lcc].x, buf[r * 33 + lcc].y);
    }
}

// K5: inverse row-DIT, write real x_enh as bf16. Block = 4 rows of one image.
__global__ void __launch_bounds__(256) ifft_rows(const unsigned* __restrict__ xf,
                                                 unsigned short* __restrict__ xe) {
    __shared__ float2 lds[512];
    int img = blockIdx.y;
    int r0 = blockIdx.x * 4;
    int t = threadIdx.x;
    const unsigned* xi = xf + (size_t)img * HWSZ + (size_t)r0 * NW;
#pragma unroll
    for (int ii = 0; ii < 2; ++ii) {
        int px = ii * 256 + t;
        unsigned u = xi[px];
        lds[px] = make_float2(bf_lo(u), bf_hi(u));
    }
    __syncthreads();
    const float PI_F = 3.14159265358979323846f;
    int j = t & 63;
    float2* row = lds + (t >> 6) * 128;
    for (int ls = 0; ls <= 6; ++ls) {
        int s = 1 << ls;
        int off = j & (s - 1);
        int i0 = ((j >> ls) << (ls + 1)) + off;
        float ang = PI_F * (float)off / (float)s;
        float sn, cs;
        __sincosf(ang, &sn, &cs);
        float2 a = row[i0];
        float2 bb = row[i0 + s];
        float tx = bb.x * cs - bb.y * sn, ty = bb.x * sn + bb.y * cs;
        row[i0] = make_float2(a.x + tx, a.y + ty);
        row[i0 + s] = make_float2(a.x - tx, a.y - ty);
        __syncthreads();
    }
    unsigned* xo = (unsigned*)xe + (((size_t)img * HWSZ + (size_t)r0 * NW) >> 1) + t;
    xo[0] = pack2(lds[2 * t].x, lds[2 * t + 1].x);
}

// K6: out = x + w_out * x_enh. c-tile 16 (grid 2048), 4 loads in flight, NT out stores.
__global__ void __launch_bounds__(256, 4) out_kernel(const float* __restrict__ x,
                                                     const float* __restrict__ w_out,
                                                     const unsigned short* __restrict__ xe,
                                                     float* __restrict__ out) {
    int b  = blockIdx.z;
    int ct = blockIdx.y;
    int p4 = blockIdx.x * 256 + threadIdx.x;
    const u32x2_t* xeb = (const u32x2_t*)(xe + (size_t)b * CMID * HWSZ);
    f32x4_t e[CMID];
#pragma unroll
    for (int m = 0; m < CMID; ++m) {
        u32x2_t u = xeb[(size_t)m * HW4 + p4];
        e[m] = (f32x4_t){ bf_lo(u.x), bf_hi(u.x), bf_lo(u.y), bf_hi(u.y) };
    }
    const f32x4_t* xb = (const f32x4_t*)(x + (size_t)b * CIN * HWSZ);
    f32x4_t* ob = (f32x4_t*)(out + (size_t)b * CIN * HWSZ);
    int c0 = ct * 16;
    for (int c = c0; c < c0 + 16; c += 4) {
        f32x4_t a0 = xb[(size_t)(c + 0) * HW4 + p4];
        f32x4_t a1 = xb[(size_t)(c + 1) * HW4 + p4];
        f32x4_t a2 = xb[(size_t)(c + 2) * HW4 + p4];
        f32x4_t a3 = xb[(size_t)(c + 3) * HW4 + p4];
#pragma unroll
        for (int m = 0; m < CMID; ++m) {
            a0 += w_out[(c + 0) * CMID + m] * e[m];
            a1 += w_out[(c + 1) * CMID + m] * e[m];
            a2 += w_out[(c + 2) * CMID + m] * e[m];
            a3 += w_out[(c + 3) * CMID + m] * e[m];
        }
        __builtin_nontemporal_store(a0, ob + (size_t)(c + 0) * HW4 + p4);
        __builtin_nontemporal_store(a1, ob + (size_t)(c + 1) * HW4 + p4);
        __builtin_nontemporal_store(a2, ob + (size_t)(c + 2) * HW4 + p4);
        __builtin_nontemporal_store(a3, ob + (size_t)(c + 3) * HW4 + p4);
    }
}

extern "C" void kernel_launch(void* const* d_in, const int* in_sizes, int n_in,
                              void* d_out, int out_size, void* d_ws, size_t ws_size,
                              hipStream_t stream) {
    const float* x     = (const float*)d_in[0];
    const float* w_in  = (const float*)d_in[1];
    const float* w_out = (const float*)d_in[2];
    const float* fw    = (const float*)d_in[3];
    float* out = (float*)d_out;

    unsigned* xfu = (unsigned*)d_ws;                                  // 8.4 MB
    float*    gain = (float*)(xfu + (size_t)NB * CMID * HWSZ);        // 1 MB
    unsigned short* xe = (unsigned short*)(gain + (size_t)CMID * HWSZ); // 4.2 MB

    gain_kernel<<<HWSZ / 256, 256, 0, stream>>>(fw, gain);
    proj_fft<<<dim3(64, NB), 512, 0, stream>>>(x, w_in, xfu);
    fft_cols_gain<<<dim3(NW / 32, NB * CMID), 256, 0, stream>>>(xfu, gain);
    ifft_rows<<<dim3(NH / 4, NB * CMID), 256, 0, stream>>>(xfu, xe);
    out_kernel<<<dim3(HW4 / 256, CIN / 16, NB), 256, 0, stream>>>(x, w_out, xe, out);
}

// Round 10
// 131.881 us; speedup vs baseline: 1.3942x; 1.3942x over previous
//
#include <hip/hip_runtime.h>
#include <math.h>

#define NB   8
#define CIN  256
#define CMID 16
#define NH   128
#define NW   128
#define HWSZ 16384
#define HW4  4096
#define NANG 8
#define NRAD 9

typedef float    f32x4_t __attribute__((ext_vector_type(4)));
typedef unsigned u32x2_t __attribute__((ext_vector_type(2)));

__device__ __forceinline__ unsigned short f2bf(float f) {
    unsigned u = __float_as_uint(f);
    u += 0x7fffu + ((u >> 16) & 1u);          // round-to-nearest-even
    return (unsigned short)(u >> 16);
}
__device__ __forceinline__ float bf_lo(unsigned u) { return __uint_as_float(u << 16); }
__device__ __forceinline__ float bf_hi(unsigned u) { return __uint_as_float(u & 0xffff0000u); }
__device__ __forceinline__ unsigned pack2(float a, float b) {
    return (unsigned)f2bf(a) | ((unsigned)f2bf(b) << 16);
}
__device__ __forceinline__ ushort4 pack4(f32x4_t v) {
    return make_ushort4(f2bf(v.x), f2bf(v.y), f2bf(v.z), f2bf(v.w));
}
__device__ __forceinline__ f32x4_t unpack4(ushort4 u) {
    return (f32x4_t){ __uint_as_float((unsigned)u.x << 16),
                      __uint_as_float((unsigned)u.y << 16),
                      __uint_as_float((unsigned)u.z << 16),
                      __uint_as_float((unsigned)u.w << 16) };
}

__device__ __forceinline__ int bitrev7(int v) {
    return (int)(__brev((unsigned)v) >> 25);
}

// Gain in bit-reversed (both dims), ifftshift-folded order, pre-scaled by 1/16384.
__global__ void __launch_bounds__(256) gain_kernel(const float* __restrict__ fw,
                                                   float* __restrict__ gain) {
    int p  = blockIdx.x * 256 + threadIdx.x;
    int py = p >> 7, px = p & 127;
    int fy = bitrev7(py), fx = bitrev7(px);
    int hy = (fy + 64) & 127, hx = (fx + 64) & 127;
    float dy = (float)(hy - 64), dx = (float)(hx - 64);
    float r = sqrtf(dy * dy + dx * dx);
    int ridx = (int)floorf(r * 0.125f);
    if (ridx > NRAD - 1) ridx = NRAD - 1;
    const float PI_F = 3.14159265358979323846f;
    float theta = fmodf(atan2f(dy, dx) + PI_F, PI_F);
    const float delta = (float)(M_PI / 8.0);
    const float hwid  = (float)(1.5 * (M_PI / 8.0) / 2.0);
    float wv[NANG];
    float wsum = 0.f;
#pragma unroll
    for (int a = 0; a < NANG; ++a) {
        float c = ((float)a + 0.5f) * delta;
        float dist = fabsf(theta - c);
        float wa = fmaxf(1.0f - dist / hwid, 0.0f);
        if (!(dist < hwid)) wa = 0.0f;
        wv[a] = wa;
        wsum += wa;
    }
    float inv = 1.0f / (wsum + 1e-8f);
#pragma unroll
    for (int m = 0; m < CMID; ++m) {
        float g = 0.f;
#pragma unroll
        for (int a = 0; a < NANG; ++a)
            g += wv[a] * fw[(m * NANG + a) * NRAD + ridx];
        gain[m * HWSZ + p] = g * inv * (1.0f / 16384.0f);
    }
}

// K2 (fused proj + row-FFT): block = (2-row strip, b), 512 threads = 8 warps.
// launch_bounds(512,2): 2 blocks/CU -> 128-VGPR cap (R9's (512,4) forced a
// 64-VGPR cap -> full accumulator spill, 288 MB scratch writes).
__global__ void __launch_bounds__(512, 2) proj_fft(const float* __restrict__ x,
                                                   const float* __restrict__ w_in,
                                                   unsigned* __restrict__ xf) {
    __shared__ ushort4 red[CMID][4][64];          // 32 KB; aliased as fftbuf[m][256]
    float2* fftbuf = (float2*)red;
    int b = blockIdx.y, strip = blockIdx.x;       // strip in [0,64)
    int t = threadIdx.x;
    int w = t >> 6, l = t & 63;

    // ---- accumulate 32 channels per warp, float4 lanes, 4-deep bursts ----
    const f32x4_t* xb = (const f32x4_t*)(x + (size_t)b * CIN * HWSZ) + strip * 64 + l;
    f32x4_t facc[CMID];
#pragma unroll
    for (int m = 0; m < CMID; ++m) facc[m] = (f32x4_t){0.f, 0.f, 0.f, 0.f};
    int c0 = w * 32;
    for (int c = c0; c < c0 + 32; c += 4) {
        f32x4_t v0 = xb[(size_t)(c + 0) * HW4];
        f32x4_t v1 = xb[(size_t)(c + 1) * HW4];
        f32x4_t v2 = xb[(size_t)(c + 2) * HW4];
        f32x4_t v3 = xb[(size_t)(c + 3) * HW4];
#pragma unroll
        for (int m = 0; m < CMID; ++m) {
            facc[m] += w_in[m * CIN + c + 0] * v0;
            facc[m] += w_in[m * CIN + c + 1] * v1;
            facc[m] += w_in[m * CIN + c + 2] * v2;
            facc[m] += w_in[m * CIN + c + 3] * v3;
        }
    }
    // ---- stage 1: warps 4-7 park partials; warps 0-3 absorb ----
    if (w >= 4) {
#pragma unroll
        for (int m = 0; m < CMID; ++m) red[m][w - 4][l] = pack4(facc[m]);
    }
    __syncthreads();
    if (w < 4) {
#pragma unroll
        for (int m = 0; m < CMID; ++m) {
            facc[m] += unpack4(red[m][w][l]);
            red[m][w][l] = pack4(facc[m]);        // same addr this thread read
        }
    }
    __syncthreads();
    // ---- stage 2: warp w owns m in {2w, 2w+1}; read 4 contributions ----
    ushort4 c4[2][4];
#pragma unroll
    for (int mm = 0; mm < 2; ++mm)
#pragma unroll
        for (int k = 0; k < 4; ++k)
            c4[mm][k] = red[2 * w + mm][k][l];
    __syncthreads();                              // all reads before aliased writes
#pragma unroll
    for (int mm = 0; mm < 2; ++mm) {
        int m = 2 * w + mm;
        f32x4_t s = unpack4(c4[mm][0]) + unpack4(c4[mm][1]) +
                    unpack4(c4[mm][2]) + unpack4(c4[mm][3]);
        fftbuf[m * 256 + 4 * l + 0] = make_float2(s.x, 0.f);
        fftbuf[m * 256 + 4 * l + 1] = make_float2(s.y, 0.f);
        fftbuf[m * 256 + 4 * l + 2] = make_float2(s.z, 0.f);
        fftbuf[m * 256 + 4 * l + 3] = make_float2(s.w, 0.f);
    }
    __syncthreads();
    // ---- 32 x 128-pt forward row-DIF FFT (rows flat at fftbuf + f*128) ----
    const float PI_F = 3.14159265358979323846f;
    int j = l;
    for (int ls = 6; ls >= 0; --ls) {
        int s = 1 << ls;
        int off = j & (s - 1);
        int i0 = ((j >> ls) << (ls + 1)) + off;
        float ang = -PI_F * (float)off / (float)s;
        float sn, cs;
        __sincosf(ang, &sn, &cs);
        for (int f = w; f < 32; f += 8) {
            float2* row = fftbuf + f * 128;
            float2 a = row[i0];
            float2 bb = row[i0 + s];
            row[i0] = make_float2(a.x + bb.x, a.y + bb.y);
            float dx_ = a.x - bb.x, dy_ = a.y - bb.y;
            row[i0 + s] = make_float2(dx_ * cs - dy_ * sn, dx_ * sn + dy_ * cs);
        }
        __syncthreads();
    }
    // ---- write packed bf16-complex xf ----
    unsigned* xo = xf + (size_t)(b * CMID) * HWSZ + strip * 256;
    for (int i = t; i < CMID * 256; i += 512) {
        int m = i >> 8, px = i & 255;
        xo[(size_t)m * HWSZ + px] = pack2(fftbuf[i].x, fftbuf[i].y);
    }
}

// K4: forward col-DIF + gain + inverse col-DIT on bf16-complex xf (in place).
__global__ void __launch_bounds__(256) fft_cols_gain(unsigned* __restrict__ xf,
                                                     const float* __restrict__ gain) {
    __shared__ float2 buf[128 * 33];
    int img = blockIdx.y;
    int m   = img & (CMID - 1);
    int c0  = blockIdx.x * 32;
    int t   = threadIdx.x;
    unsigned* xi = xf + (size_t)img * HWSZ;

    for (int idx = t; idx < 128 * 32; idx += 256) {
        int r = idx >> 5, lc = idx & 31;
        unsigned u = xi[r * NW + c0 + lc];
        buf[r * 33 + lc] = make_float2(bf_lo(u), bf_hi(u));
    }
    __syncthreads();
    const float PI_F = 3.14159265358979323846f;
    int lc = t & 31;
    int jb = t >> 5;
    for (int ls = 6; ls >= 0; --ls) {
        int s = 1 << ls;
        for (int j = jb; j < 64; j += 8) {
            int off = j & (s - 1);
            int i0 = ((j >> ls) << (ls + 1)) + off;
            float ang = -PI_F * (float)off / (float)s;
            float sn, cs;
            __sincosf(ang, &sn, &cs);
            float2 a = buf[i0 * 33 + lc];
            float2 bb = buf[(i0 + s) * 33 + lc];
            buf[i0 * 33 + lc] = make_float2(a.x + bb.x, a.y + bb.y);
            float dx_ = a.x - bb.x, dy_ = a.y - bb.y;
            buf[(i0 + s) * 33 + lc] = make_float2(dx_ * cs - dy_ * sn, dx_ * sn + dy_ * cs);
        }
        __syncthreads();
    }
    {
        const float* gm = gain + (size_t)m * HWSZ;
        for (int idx = t; idx < 128 * 32; idx += 256) {
            int r = idx >> 5, lcc = idx & 31;
            float g = gm[r * NW + c0 + lcc];
            buf[r * 33 + lcc].x *= g;
            buf[r * 33 + lcc].y *= g;
        }
        __syncthreads();
    }
    for (int ls = 0; ls <= 6; ++ls) {
        int s = 1 << ls;
        for (int j = jb; j < 64; j += 8) {
            int off = j & (s - 1);
            int i0 = ((j >> ls) << (ls + 1)) + off;
            float ang = PI_F * (float)off / (float)s;
            float sn, cs;
            __sincosf(ang, &sn, &cs);
            float2 a = buf[i0 * 33 + lc];
            float2 bb = buf[(i0 + s) * 33 + lc];
            float tx = bb.x * cs - bb.y * sn, ty = bb.x * sn + bb.y * cs;
            buf[i0 * 33 + lc] = make_float2(a.x + tx, a.y + ty);
            buf[(i0 + s) * 33 + lc] = make_float2(a.x - tx, a.y - ty);
        }
        __syncthreads();
    }
    for (int idx = t; idx < 128 * 32; idx += 256) {
        int r = idx >> 5, lcc = idx & 31;
        xi[r * NW + c0 + lcc] = pack2(buf[r * 33 + lcc].x, buf[r * 33 + lcc].y);
    }
}

// K5: inverse row-DIT, write real x_enh as bf16. Block = 4 rows of one image.
__global__ void __launch_bounds__(256) ifft_rows(const unsigned* __restrict__ xf,
                                                 unsigned short* __restrict__ xe) {
    __shared__ float2 lds[512];
    int img = blockIdx.y;
    int r0 = blockIdx.x * 4;
    int t = threadIdx.x;
    const unsigned* xi = xf + (size_t)img * HWSZ + (size_t)r0 * NW;
#pragma unroll
    for (int ii = 0; ii < 2; ++ii) {
        int px = ii * 256 + t;
        unsigned u = xi[px];
        lds[px] = make_float2(bf_lo(u), bf_hi(u));
    }
    __syncthreads();
    const float PI_F = 3.14159265358979323846f;
    int j = t & 63;
    float2* row = lds + (t >> 6) * 128;
    for (int ls = 0; ls <= 6; ++ls) {
        int s = 1 << ls;
        int off = j & (s - 1);
        int i0 = ((j >> ls) << (ls + 1)) + off;
        float ang = PI_F * (float)off / (float)s;
        float sn, cs;
        __sincosf(ang, &sn, &cs);
        float2 a = row[i0];
        float2 bb = row[i0 + s];
        float tx = bb.x * cs - bb.y * sn, ty = bb.x * sn + bb.y * cs;
        row[i0] = make_float2(a.x + tx, a.y + ty);
        row[i0 + s] = make_float2(a.x - tx, a.y - ty);
        __syncthreads();
    }
    unsigned* xo = (unsigned*)xe + (((size_t)img * HWSZ + (size_t)r0 * NW) >> 1) + t;
    xo[0] = pack2(lds[2 * t].x, lds[2 * t + 1].x);
}

// K6: out = x + w_out * x_enh. c-tile 16 (grid 2048), 4 loads in flight, NT out stores.
__global__ void __launch_bounds__(256, 4) out_kernel(const float* __restrict__ x,
                                                     const float* __restrict__ w_out,
                                                     const unsigned short* __restrict__ xe,
                                                     float* __restrict__ out) {
    int b  = blockIdx.z;
    int ct = blockIdx.y;
    int p4 = blockIdx.x * 256 + threadIdx.x;
    const u32x2_t* xeb = (const u32x2_t*)(xe + (size_t)b * CMID * HWSZ);
    f32x4_t e[CMID];
#pragma unroll
    for (int m = 0; m < CMID; ++m) {
        u32x2_t u = xeb[(size_t)m * HW4 + p4];
        e[m] = (f32x4_t){ bf_lo(u.x), bf_hi(u.x), bf_lo(u.y), bf_hi(u.y) };
    }
    const f32x4_t* xb = (const f32x4_t*)(x + (size_t)b * CIN * HWSZ);
    f32x4_t* ob = (f32x4_t*)(out + (size_t)b * CIN * HWSZ);
    int c0 = ct * 16;
    for (int c = c0; c < c0 + 16; c += 4) {
        f32x4_t a0 = xb[(size_t)(c + 0) * HW4 + p4];
        f32x4_t a1 = xb[(size_t)(c + 1) * HW4 + p4];
        f32x4_t a2 = xb[(size_t)(c + 2) * HW4 + p4];
        f32x4_t a3 = xb[(size_t)(c + 3) * HW4 + p4];
#pragma unroll
        for (int m = 0; m < CMID; ++m) {
            a0 += w_out[(c + 0) * CMID + m] * e[m];
            a1 += w_out[(c + 1) * CMID + m] * e[m];
            a2 += w_out[(c + 2) * CMID + m] * e[m];
            a3 += w_out[(c + 3) * CMID + m] * e[m];
        }
        __builtin_nontemporal_store(a0, ob + (size_t)(c + 0) * HW4 + p4);
        __builtin_nontemporal_store(a1, ob + (size_t)(c + 1) * HW4 + p4);
        __builtin_nontemporal_store(a2, ob + (size_t)(c + 2) * HW4 + p4);
        __builtin_nontemporal_store(a3, ob + (size_t)(c + 3) * HW4 + p4);
    }
}

extern "C" void kernel_launch(void* const* d_in, const int* in_sizes, int n_in,
                              void* d_out, int out_size, void* d_ws, size_t ws_size,
                              hipStream_t stream) {
    const float* x     = (const float*)d_in[0];
    const float* w_in  = (const float*)d_in[1];
    const float* w_out = (const float*)d_in[2];
    const float* fw    = (const float*)d_in[3];
    float* out = (float*)d_out;

    unsigned* xfu = (unsigned*)d_ws;                                  // 8.4 MB
    float*    gain = (float*)(xfu + (size_t)NB * CMID * HWSZ);        // 1 MB
    unsigned short* xe = (unsigned short*)(gain + (size_t)CMID * HWSZ); // 4.2 MB

    gain_kernel<<<HWSZ / 256, 256, 0, stream>>>(fw, gain);
    proj_fft<<<dim3(64, NB), 512, 0, stream>>>(x, w_in, xfu);
    fft_cols_gain<<<dim3(NW / 32, NB * CMID), 256, 0, stream>>>(xfu, gain);
    ifft_rows<<<dim3(NH / 4, NB * CMID), 256, 0, stream>>>(xfu, xe);
    out_kernel<<<dim3(HW4 / 256, CIN / 16, NB), 256, 0, stream>>>(x, w_out, xe, out);
}

// Round 11
// 116.393 us; speedup vs baseline: 1.5797x; 1.1331x over previous
//
#include <hip/hip_runtime.h>
#include <math.h>

#define NB   8
#define CIN  256
#define CMID 16
#define NH   128
#define NW   128
#define HWSZ 16384
#define HW4  4096
#define NANG 8
#define NRAD 9

typedef float    f32x4_t __attribute__((ext_vector_type(4)));
typedef unsigned u32x2_t __attribute__((ext_vector_type(2)));

__device__ __forceinline__ unsigned short f2bf(float f) {
    unsigned u = __float_as_uint(f);
    u += 0x7fffu + ((u >> 16) & 1u);          // round-to-nearest-even
    return (unsigned short)(u >> 16);
}
__device__ __forceinline__ float bf_lo(unsigned u) { return __uint_as_float(u << 16); }
__device__ __forceinline__ float bf_hi(unsigned u) { return __uint_as_float(u & 0xffff0000u); }
__device__ __forceinline__ unsigned pack2(float a, float b) {
    return (unsigned)f2bf(a) | ((unsigned)f2bf(b) << 16);
}

__device__ __forceinline__ int bitrev7(int v) {
    return (int)(__brev((unsigned)v) >> 25);
}

// Gain in bit-reversed (both dims), ifftshift-folded order, pre-scaled by 1/16384.
__global__ void __launch_bounds__(256) gain_kernel(const float* __restrict__ fw,
                                                   float* __restrict__ gain) {
    int p  = blockIdx.x * 256 + threadIdx.x;
    int py = p >> 7, px = p & 127;
    int fy = bitrev7(py), fx = bitrev7(px);
    int hy = (fy + 64) & 127, hx = (fx + 64) & 127;
    float dy = (float)(hy - 64), dx = (float)(hx - 64);
    float r = sqrtf(dy * dy + dx * dx);
    int ridx = (int)floorf(r * 0.125f);
    if (ridx > NRAD - 1) ridx = NRAD - 1;
    const float PI_F = 3.14159265358979323846f;
    float theta = fmodf(atan2f(dy, dx) + PI_F, PI_F);
    const float delta = (float)(M_PI / 8.0);
    const float hwid  = (float)(1.5 * (M_PI / 8.0) / 2.0);
    float wv[NANG];
    float wsum = 0.f;
#pragma unroll
    for (int a = 0; a < NANG; ++a) {
        float c = ((float)a + 0.5f) * delta;
        float dist = fabsf(theta - c);
        float wa = fmaxf(1.0f - dist / hwid, 0.0f);
        if (!(dist < hwid)) wa = 0.0f;
        wv[a] = wa;
        wsum += wa;
    }
    float inv = 1.0f / (wsum + 1e-8f);
#pragma unroll
    for (int m = 0; m < CMID; ++m) {
        float g = 0.f;
#pragma unroll
        for (int a = 0; a < NANG; ++a)
            g += wv[a] * fw[(m * NANG + a) * NRAD + ridx];
        gain[m * HWSZ + p] = g * inv * (1.0f / 16384.0f);
    }
}

// K2: split-K projection, float4 lanes, 8 loads in flight, bf16 partial stores.
__global__ void __launch_bounds__(256, 4) proj_partial(const float* __restrict__ x,
                                                       const float* __restrict__ w_in,
                                                       unsigned short* __restrict__ partials,
                                                       int nchunk) {
    int b  = blockIdx.z;
    int ck = blockIdx.y;
    int p4 = blockIdx.x * 256 + threadIdx.x;          // float4 index, 4096/image
    int cpc = CIN / nchunk;
    int c0 = ck * cpc;
    const f32x4_t* xb = (const f32x4_t*)(x + (size_t)b * CIN * HWSZ);
    f32x4_t acc[CMID];
#pragma unroll
    for (int m = 0; m < CMID; ++m) acc[m] = (f32x4_t){0.f, 0.f, 0.f, 0.f};
    for (int c = c0; c < c0 + cpc; c += 8) {
        f32x4_t v[8];
#pragma unroll
        for (int k = 0; k < 8; ++k)
            v[k] = xb[(size_t)(c + k) * HW4 + p4];
#pragma unroll
        for (int k = 0; k < 8; ++k) {
#pragma unroll
            for (int m = 0; m < CMID; ++m)
                acc[m] += w_in[m * CIN + c + k] * v[k];
        }
    }
    ushort4* pb = (ushort4*)partials + ((size_t)(b * nchunk + ck) * CMID) * HW4;
#pragma unroll
    for (int m = 0; m < CMID; ++m)
        pb[(size_t)m * HW4 + p4] = make_ushort4(f2bf(acc[m].x), f2bf(acc[m].y),
                                                f2bf(acc[m].z), f2bf(acc[m].w));
}

// K3: reduce bf16 partials + forward row-DIF FFT.
__global__ void __launch_bounds__(256) reduce_fft_rows(const unsigned short* __restrict__ partials,
                                                       unsigned* __restrict__ xf,
                                                       int nchunk) {
    __shared__ float2 lds[512];
    int img = blockIdx.y;                             // b*16 + m
    int b = img >> 4, m = img & 15;
    int r0 = blockIdx.x * 4;
    int t = threadIdx.x;
    const unsigned* pbase = (const unsigned*)(partials +
        ((size_t)(b * nchunk) * CMID + m) * HWSZ + (size_t)r0 * NW) + t;
    size_t cks = (size_t)CMID * HWSZ / 2;             // uints per chunk
    float sx = 0.f, sy = 0.f;
    if (nchunk == 8) {
#pragma unroll
        for (int ck = 0; ck < 8; ++ck) {
            unsigned u = pbase[(size_t)ck * cks];
            sx += bf_lo(u); sy += bf_hi(u);
        }
    } else {
        for (int ck = 0; ck < nchunk; ++ck) {
            unsigned u = pbase[(size_t)ck * cks];
            sx += bf_lo(u); sy += bf_hi(u);
        }
    }
    lds[2 * t]     = make_float2(sx, 0.f);
    lds[2 * t + 1] = make_float2(sy, 0.f);
    __syncthreads();
    const float PI_F = 3.14159265358979323846f;
    int j = t & 63;
    float2* row = lds + (t >> 6) * 128;
    for (int ls = 6; ls >= 0; --ls) {
        int s = 1 << ls;
        int off = j & (s - 1);
        int i0 = ((j >> ls) << (ls + 1)) + off;
        float ang = -PI_F * (float)off / (float)s;
        float sn, cs;
        __sincosf(ang, &sn, &cs);
        float2 a = row[i0];
        float2 bb = row[i0 + s];
        row[i0] = make_float2(a.x + bb.x, a.y + bb.y);
        float dx_ = a.x - bb.x, dy_ = a.y - bb.y;
        row[i0 + s] = make_float2(dx_ * cs - dy_ * sn, dx_ * sn + dy_ * cs);
        __syncthreads();
    }
    unsigned* xo = xf + (size_t)img * HWSZ + (size_t)r0 * NW;
#pragma unroll
    for (int ii = 0; ii < 2; ++ii) {
        int px = ii * 256 + t;
        xo[px] = pack2(lds[px].x, lds[px].y);
    }
}

// K4: forward col-DIF + gain + inverse col-DIT on bf16-complex xf (in place).
__global__ void __launch_bounds__(256) fft_cols_gain(unsigned* __restrict__ xf,
                                                     const float* __restrict__ gain) {
    __shared__ float2 buf[128 * 33];
    int img = blockIdx.y;
    int m   = img & (CMID - 1);
    int c0  = blockIdx.x * 32;
    int t   = threadIdx.x;
    unsigned* xi = xf + (size_t)img * HWSZ;

    for (int idx = t; idx < 128 * 32; idx += 256) {
        int r = idx >> 5, lc = idx & 31;
        unsigned u = xi[r * NW + c0 + lc];
        buf[r * 33 + lc] = make_float2(bf_lo(u), bf_hi(u));
    }
    __syncthreads();
    const float PI_F = 3.14159265358979323846f;
    int lc = t & 31;
    int jb = t >> 5;
    for (int ls = 6; ls >= 0; --ls) {
        int s = 1 << ls;
        for (int j = jb; j < 64; j += 8) {
            int off = j & (s - 1);
            int i0 = ((j >> ls) << (ls + 1)) + off;
            float ang = -PI_F * (float)off / (float)s;
            float sn, cs;
            __sincosf(ang, &sn, &cs);
            float2 a = buf[i0 * 33 + lc];
            float2 bb = buf[(i0 + s) * 33 + lc];
            buf[i0 * 33 + lc] = make_float2(a.x + bb.x, a.y + bb.y);
            float dx_ = a.x - bb.x, dy_ = a.y - bb.y;
            buf[(i0 + s) * 33 + lc] = make_float2(dx_ * cs - dy_ * sn, dx_ * sn + dy_ * cs);
        }
        __syncthreads();
    }
    {
        const float* gm = gain + (size_t)m * HWSZ;
        for (int idx = t; idx < 128 * 32; idx += 256) {
            int r = idx >> 5, lcc = idx & 31;
            float g = gm[r * NW + c0 + lcc];
            buf[r * 33 + lcc].x *= g;
            buf[r * 33 + lcc].y *= g;
        }
        __syncthreads();
    }
    for (int ls = 0; ls <= 6; ++ls) {
        int s = 1 << ls;
        for (int j = jb; j < 64; j += 8) {
            int off = j & (s - 1);
            int i0 = ((j >> ls) << (ls + 1)) + off;
            float ang = PI_F * (float)off / (float)s;
            float sn, cs;
            __sincosf(ang, &sn, &cs);
            float2 a = buf[i0 * 33 + lc];
            float2 bb = buf[(i0 + s) * 33 + lc];
            float tx = bb.x * cs - bb.y * sn, ty = bb.x * sn + bb.y * cs;
            buf[i0 * 33 + lc] = make_float2(a.x + tx, a.y + ty);
            buf[(i0 + s) * 33 + lc] = make_float2(a.x - tx, a.y - ty);
        }
        __syncthreads();
    }
    for (int idx = t; idx < 128 * 32; idx += 256) {
        int r = idx >> 5, lcc = idx & 31;
        xi[r * NW + c0 + lcc] = pack2(buf[r * 33 + lcc].x, buf[r * 33 + lcc].y);
    }
}

// K5: inverse row-DIT, write real x_enh as bf16. Block = 4 rows of one image.
__global__ void __launch_bounds__(256) ifft_rows(const unsigned* __restrict__ xf,
                                                 unsigned short* __restrict__ xe) {
    __shared__ float2 lds[512];
    int img = blockIdx.y;
    int r0 = blockIdx.x * 4;
    int t = threadIdx.x;
    const unsigned* xi = xf + (size_t)img * HWSZ + (size_t)r0 * NW;
#pragma unroll
    for (int ii = 0; ii < 2; ++ii) {
        int px = ii * 256 + t;
        unsigned u = xi[px];
        lds[px] = make_float2(bf_lo(u), bf_hi(u));
    }
    __syncthreads();
    const float PI_F = 3.14159265358979323846f;
    int j = t & 63;
    float2* row = lds + (t >> 6) * 128;
    for (int ls = 0; ls <= 6; ++ls) {
        int s = 1 << ls;
        int off = j & (s - 1);
        int i0 = ((j >> ls) << (ls + 1)) + off;
        float ang = PI_F * (float)off / (float)s;
        float sn, cs;
        __sincosf(ang, &sn, &cs);
        float2 a = row[i0];
        float2 bb = row[i0 + s];
        float tx = bb.x * cs - bb.y * sn, ty = bb.x * sn + bb.y * cs;
        row[i0] = make_float2(a.x + tx, a.y + ty);
        row[i0 + s] = make_float2(a.x - tx, a.y - ty);
        __syncthreads();
    }
    unsigned* xo = (unsigned*)xe + (((size_t)img * HWSZ + (size_t)r0 * NW) >> 1) + t;
    xo[0] = pack2(lds[2 * t].x, lds[2 * t + 1].x);
}

// K6: out = x + w_out * x_enh. c-tile 16 (grid 2048), 8 loads in flight, NT out stores.
__global__ void __launch_bounds__(256, 4) out_kernel(const float* __restrict__ x,
                                                     const float* __restrict__ w_out,
                                                     const unsigned short* __restrict__ xe,
                                                     float* __restrict__ out) {
    int b  = blockIdx.z;
    int ct = blockIdx.y;
    int p4 = blockIdx.x * 256 + threadIdx.x;
    const u32x2_t* xeb = (const u32x2_t*)(xe + (size_t)b * CMID * HWSZ);
    f32x4_t e[CMID];
#pragma unroll
    for (int m = 0; m < CMID; ++m) {
        u32x2_t u = xeb[(size_t)m * HW4 + p4];
        e[m] = (f32x4_t){ bf_lo(u.x), bf_hi(u.x), bf_lo(u.y), bf_hi(u.y) };
    }
    const f32x4_t* xb = (const f32x4_t*)(x + (size_t)b * CIN * HWSZ);
    f32x4_t* ob = (f32x4_t*)(out + (size_t)b * CIN * HWSZ);
    int c0 = ct * 16;
    for (int c = c0; c < c0 + 16; c += 8) {
        f32x4_t a[8];
#pragma unroll
        for (int k = 0; k < 8; ++k)
            a[k] = xb[(size_t)(c + k) * HW4 + p4];
#pragma unroll
        for (int m = 0; m < CMID; ++m) {
#pragma unroll
            for (int k = 0; k < 8; ++k)
                a[k] += w_out[(c + k) * CMID + m] * e[m];
        }
#pragma unroll
        for (int k = 0; k < 8; ++k)
            __builtin_nontemporal_store(a[k], ob + (size_t)(c + k) * HW4 + p4);
    }
}

extern "C" void kernel_launch(void* const* d_in, const int* in_sizes, int n_in,
                              void* d_out, int out_size, void* d_ws, size_t ws_size,
                              hipStream_t stream) {
    const float* x     = (const float*)d_in[0];
    const float* w_in  = (const float*)d_in[1];
    const float* w_out = (const float*)d_in[2];
    const float* fw    = (const float*)d_in[3];
    float* out = (float*)d_out;

    int nchunk = 8;
    while (nchunk > 1) {
        size_t need = (size_t)NB * nchunk * CMID * HWSZ * 2   // partials bf16
                    + (size_t)NB * CMID * HWSZ * 4            // xf bf16-complex
                    + (size_t)CMID * HWSZ * 4;                // gain fp32
        if (need <= ws_size) break;
        nchunk >>= 1;
    }
    unsigned short* partials = (unsigned short*)d_ws;
    unsigned* xfu = (unsigned*)(partials + (size_t)NB * nchunk * CMID * HWSZ);
    float*    gain = (float*)(xfu + (size_t)NB * CMID * HWSZ);
    unsigned short* xe = partials;                    // reuse (4 MB <= partials size)

    gain_kernel<<<HWSZ / 256, 256, 0, stream>>>(fw, gain);
    proj_partial<<<dim3(HW4 / 256, nchunk, NB), 256, 0, stream>>>(x, w_in, partials, nchunk);
    reduce_fft_rows<<<dim3(NH / 4, NB * CMID), 256, 0, stream>>>(partials, xfu, nchunk);
    fft_cols_gain<<<dim3(NW / 32, NB * CMID), 256, 0, stream>>>(xfu, gain);
    ifft_rows<<<dim3(NH / 4, NB * CMID), 256, 0, stream>>>(xfu, xe);
    out_kernel<<<dim3(HW4 / 256, CIN / 16, NB), 256, 0, stream>>>(x, w_out, xe, out);
}

// Round 12
// 110.950 us; speedup vs baseline: 1.6572x; 1.0491x over previous
//
#include <hip/hip_runtime.h>
#include <math.h>

#define NB   8
#define CIN  256
#define CMID 16
#define NH   128
#define NW   128
#define HWSZ 16384
#define HW4  4096
#define NANG 8
#define NRAD 9

typedef float    f32x4_t __attribute__((ext_vector_type(4)));
typedef unsigned u32x2_t __attribute__((ext_vector_type(2)));

__device__ __forceinline__ unsigned short f2bf(float f) {
    unsigned u = __float_as_uint(f);
    u += 0x7fffu + ((u >> 16) & 1u);          // round-to-nearest-even
    return (unsigned short)(u >> 16);
}
__device__ __forceinline__ float bf_lo(unsigned u) { return __uint_as_float(u << 16); }
__device__ __forceinline__ float bf_hi(unsigned u) { return __uint_as_float(u & 0xffff0000u); }
__device__ __forceinline__ unsigned pack2(float a, float b) {
    return (unsigned)f2bf(a) | ((unsigned)f2bf(b) << 16);
}

__device__ __forceinline__ int bitrev7(int v) {
    return (int)(__brev((unsigned)v) >> 25);
}

// Gain in bit-reversed (both dims), ifftshift-folded order, pre-scaled by 1/16384.
__global__ void __launch_bounds__(256) gain_kernel(const float* __restrict__ fw,
                                                   float* __restrict__ gain) {
    int p  = blockIdx.x * 256 + threadIdx.x;
    int py = p >> 7, px = p & 127;
    int fy = bitrev7(py), fx = bitrev7(px);
    int hy = (fy + 64) & 127, hx = (fx + 64) & 127;
    float dy = (float)(hy - 64), dx = (float)(hx - 64);
    float r = sqrtf(dy * dy + dx * dx);
    int ridx = (int)floorf(r * 0.125f);
    if (ridx > NRAD - 1) ridx = NRAD - 1;
    const float PI_F = 3.14159265358979323846f;
    float theta = fmodf(atan2f(dy, dx) + PI_F, PI_F);
    const float delta = (float)(M_PI / 8.0);
    const float hwid  = (float)(1.5 * (M_PI / 8.0) / 2.0);
    float wv[NANG];
    float wsum = 0.f;
#pragma unroll
    for (int a = 0; a < NANG; ++a) {
        float c = ((float)a + 0.5f) * delta;
        float dist = fabsf(theta - c);
        float wa = fmaxf(1.0f - dist / hwid, 0.0f);
        if (!(dist < hwid)) wa = 0.0f;
        wv[a] = wa;
        wsum += wa;
    }
    float inv = 1.0f / (wsum + 1e-8f);
#pragma unroll
    for (int m = 0; m < CMID; ++m) {
        float g = 0.f;
#pragma unroll
        for (int a = 0; a < NANG; ++a)
            g += wv[a] * fw[(m * NANG + a) * NRAD + ridx];
        gain[m * HWSZ + p] = g * inv * (1.0f / 16384.0f);
    }
}

// K2: split-K projection, float4 lanes, 8 loads in flight, bf16 partial stores.
__global__ void __launch_bounds__(256, 4) proj_partial(const float* __restrict__ x,
                                                       const float* __restrict__ w_in,
                                                       unsigned short* __restrict__ partials,
                                                       int nchunk) {
    int b  = blockIdx.z;
    int ck = blockIdx.y;
    int p4 = blockIdx.x * 256 + threadIdx.x;          // float4 index, 4096/image
    int cpc = CIN / nchunk;
    int c0 = ck * cpc;
    const f32x4_t* xb = (const f32x4_t*)(x + (size_t)b * CIN * HWSZ);
    f32x4_t acc[CMID];
#pragma unroll
    for (int m = 0; m < CMID; ++m) acc[m] = (f32x4_t){0.f, 0.f, 0.f, 0.f};
    for (int c = c0; c < c0 + cpc; c += 8) {
        f32x4_t v[8];
#pragma unroll
        for (int k = 0; k < 8; ++k)
            v[k] = xb[(size_t)(c + k) * HW4 + p4];
#pragma unroll
        for (int k = 0; k < 8; ++k) {
#pragma unroll
            for (int m = 0; m < CMID; ++m)
                acc[m] += w_in[m * CIN + c + k] * v[k];
        }
    }
    ushort4* pb = (ushort4*)partials + ((size_t)(b * nchunk + ck) * CMID) * HW4;
#pragma unroll
    for (int m = 0; m < CMID; ++m)
        pb[(size_t)m * HW4 + p4] = make_ushort4(f2bf(acc[m].x), f2bf(acc[m].y),
                                                f2bf(acc[m].z), f2bf(acc[m].w));
}

// K3: reduce bf16 partials + forward row-DIF FFT.
__global__ void __launch_bounds__(256) reduce_fft_rows(const unsigned short* __restrict__ partials,
                                                       unsigned* __restrict__ xf,
                                                       int nchunk) {
    __shared__ float2 lds[512];
    int img = blockIdx.y;                             // b*16 + m
    int b = img >> 4, m = img & 15;
    int r0 = blockIdx.x * 4;
    int t = threadIdx.x;
    const unsigned* pbase = (const unsigned*)(partials +
        ((size_t)(b * nchunk) * CMID + m) * HWSZ + (size_t)r0 * NW) + t;
    size_t cks = (size_t)CMID * HWSZ / 2;             // uints per chunk
    float sx = 0.f, sy = 0.f;
    if (nchunk == 8) {
#pragma unroll
        for (int ck = 0; ck < 8; ++ck) {
            unsigned u = pbase[(size_t)ck * cks];
            sx += bf_lo(u); sy += bf_hi(u);
        }
    } else {
        for (int ck = 0; ck < nchunk; ++ck) {
            unsigned u = pbase[(size_t)ck * cks];
            sx += bf_lo(u); sy += bf_hi(u);
        }
    }
    lds[2 * t]     = make_float2(sx, 0.f);
    lds[2 * t + 1] = make_float2(sy, 0.f);
    __syncthreads();
    const float PI_F = 3.14159265358979323846f;
    int j = t & 63;
    float2* row = lds + (t >> 6) * 128;
    for (int ls = 6; ls >= 0; --ls) {
        int s = 1 << ls;
        int off = j & (s - 1);
        int i0 = ((j >> ls) << (ls + 1)) + off;
        float ang = -PI_F * (float)off / (float)s;
        float sn, cs;
        __sincosf(ang, &sn, &cs);
        float2 a = row[i0];
        float2 bb = row[i0 + s];
        row[i0] = make_float2(a.x + bb.x, a.y + bb.y);
        float dx_ = a.x - bb.x, dy_ = a.y - bb.y;
        row[i0 + s] = make_float2(dx_ * cs - dy_ * sn, dx_ * sn + dy_ * cs);
        __syncthreads();
    }
    unsigned* xo = xf + (size_t)img * HWSZ + (size_t)r0 * NW;
#pragma unroll
    for (int ii = 0; ii < 2; ++ii) {
        int px = ii * 256 + t;
        xo[px] = pack2(lds[px].x, lds[px].y);
    }
}

// K4: radix-2^2 col FFT + gain + inverse, 8 barrier phases (was 15).
// Fused stage-pairs keep exact radix-2 element ordering, so the pre-permuted
// gain table indexing is unchanged. Middle phase fuses fwd-s1 + gain + inv-s1.
__global__ void __launch_bounds__(256) fft_cols_gain(unsigned* __restrict__ xf,
                                                     const float* __restrict__ gain) {
    __shared__ float2 buf[128 * 33];
    int img = blockIdx.y;
    int m   = img & (CMID - 1);
    int c0  = blockIdx.x * 32;
    int t   = threadIdx.x;
    unsigned* xi = xf + (size_t)img * HWSZ;

    for (int idx = t; idx < 4096; idx += 256) {
        int r = idx >> 5, lc = idx & 31;
        unsigned u = xi[r * NW + c0 + lc];
        buf[r * 33 + lc] = make_float2(bf_lo(u), bf_hi(u));
    }
    __syncthreads();
    const float PI_F = 3.14159265358979323846f;
    int lc = t & 31;
    int kb = t >> 5;                              // 0..7
    // ---- forward DIF, fused pairs: (s,h) = (64,32),(16,8),(4,2) ----
    for (int sp = 6; sp >= 2; sp -= 2) {
        int s = 1 << sp, h = s >> 1;
        for (int k = kb; k < 32; k += 8) {
            int o = k & (h - 1);
            int i0 = ((k >> (sp - 1)) << (sp + 1)) + o;
            float ang = -PI_F * (float)o / (float)s;
            float sn, cs;
            __sincosf(ang, &sn, &cs);
            float wbc = cs * cs - sn * sn, wbs = 2.f * cs * sn;   // WB = WA^2
            float2 x0 = buf[i0 * 33 + lc],       x1 = buf[(i0 + h) * 33 + lc];
            float2 x2 = buf[(i0 + s) * 33 + lc], x3 = buf[(i0 + s + h) * 33 + lc];
            // stage stride s: pairs (x0,x2) twiddle WA, (x1,x3) twiddle WA*(-i)
            float2 y0 = make_float2(x0.x + x2.x, x0.y + x2.y);
            float dx = x0.x - x2.x, dy = x0.y - x2.y;
            float2 y2 = make_float2(dx * cs - dy * sn, dx * sn + dy * cs);
            float2 y1 = make_float2(x1.x + x3.x, x1.y + x3.y);
            dx = x1.x - x3.x; dy = x1.y - x3.y;
            float2 y3 = make_float2(dx * sn + dy * cs, dy * sn - dx * cs);
            // stage stride h: pairs (y0,y1), (y2,y3), twiddle WB
            float2 z0 = make_float2(y0.x + y1.x, y0.y + y1.y);
            dx = y0.x - y1.x; dy = y0.y - y1.y;
            float2 z1 = make_float2(dx * wbc - dy * wbs, dx * wbs + dy * wbc);
            float2 z2 = make_float2(y2.x + y3.x, y2.y + y3.y);
            dx = y2.x - y3.x; dy = y2.y - y3.y;
            float2 z3 = make_float2(dx * wbc - dy * wbs, dx * wbs + dy * wbc);
            buf[i0 * 33 + lc] = z0;       buf[(i0 + h) * 33 + lc] = z1;
            buf[(i0 + s) * 33 + lc] = z2; buf[(i0 + s + h) * 33 + lc] = z3;
        }
        __syncthreads();
    }
    // ---- middle: fwd s=1 (W=1) + gain + inv s=1 (W=1), one LDS pass ----
    {
        const float* gm = gain + (size_t)m * HWSZ + c0;
        for (int idx = t; idx < 2048; idx += 256) {
            int i0 = (idx >> 5) * 2, lc2 = idx & 31;
            float2 a = buf[i0 * 33 + lc2], b = buf[(i0 + 1) * 33 + lc2];
            float g0 = gm[i0 * NW + lc2], g1 = gm[(i0 + 1) * NW + lc2];
            float v0x = (a.x + b.x) * g0, v0y = (a.y + b.y) * g0;
            float v1x = (a.x - b.x) * g1, v1y = (a.y - b.y) * g1;
            buf[i0 * 33 + lc2]       = make_float2(v0x + v1x, v0y + v1y);
            buf[(i0 + 1) * 33 + lc2] = make_float2(v0x - v1x, v0y - v1y);
        }
        __syncthreads();
    }
    // ---- inverse DIT, fused pairs: (h,s) = (2,4),(8,16),(32,64) ----
    for (int sp = 2; sp <= 6; sp += 2) {
        int s = 1 << sp, h = s >> 1;
        for (int k = kb; k < 32; k += 8) {
            int o = k & (h - 1);
            int i0 = ((k >> (sp - 1)) << (sp + 1)) + o;
            float ang = PI_F * (float)o / (float)s;
            float sn, cs;
            __sincosf(ang, &sn, &cs);
            float wbc = cs * cs - sn * sn, wbs = 2.f * cs * sn;   // WB = WA^2
            float2 x0 = buf[i0 * 33 + lc],       x1 = buf[(i0 + h) * 33 + lc];
            float2 x2 = buf[(i0 + s) * 33 + lc], x3 = buf[(i0 + s + h) * 33 + lc];
            // stage stride h: (x0,x1),(x2,x3) with WB
            float tx = x1.x * wbc - x1.y * wbs, ty = x1.x * wbs + x1.y * wbc;
            float2 y0 = make_float2(x0.x + tx, x0.y + ty);
            float2 y1 = make_float2(x0.x - tx, x0.y - ty);
            tx = x3.x * wbc - x3.y * wbs; ty = x3.x * wbs + x3.y * wbc;
            float2 y2 = make_float2(x2.x + tx, x2.y + ty);
            float2 y3 = make_float2(x2.x - tx, x2.y - ty);
            // stage stride s: (y0,y2) twiddle WA; (y1,y3) twiddle i*WA
            tx = y2.x * cs - y2.y * sn; ty = y2.x * sn + y2.y * cs;
            float2 z0 = make_float2(y0.x + tx, y0.y + ty);
            float2 z2 = make_float2(y0.x - tx, y0.y - ty);
            tx = -y3.x * sn - y3.y * cs; ty = y3.x * cs - y3.y * sn;
            float2 z1 = make_float2(y1.x + tx, y1.y + ty);
            float2 z3 = make_float2(y1.x - tx, y1.y - ty);
            buf[i0 * 33 + lc] = z0;       buf[(i0 + h) * 33 + lc] = z1;
            buf[(i0 + s) * 33 + lc] = z2; buf[(i0 + s + h) * 33 + lc] = z3;
        }
        __syncthreads();
    }
    for (int idx = t; idx < 4096; idx += 256) {
        int r = idx >> 5, lc2 = idx & 31;
        xi[r * NW + c0 + lc2] = pack2(buf[r * 33 + lc2].x, buf[r * 33 + lc2].y);
    }
}

// K5: inverse row-DIT, write real x_enh as bf16. Block = 4 rows of one image.
__global__ void __launch_bounds__(256) ifft_rows(const unsigned* __restrict__ xf,
                                                 unsigned short* __restrict__ xe) {
    __shared__ float2 lds[512];
    int img = blockIdx.y;
    int r0 = blockIdx.x * 4;
    int t = threadIdx.x;
    const unsigned* xi = xf + (size_t)img * HWSZ + (size_t)r0 * NW;
#pragma unroll
    for (int ii = 0; ii < 2; ++ii) {
        int px = ii * 256 + t;
        unsigned u = xi[px];
        lds[px] = make_float2(bf_lo(u), bf_hi(u));
    }
    __syncthreads();
    const float PI_F = 3.14159265358979323846f;
    int j = t & 63;
    float2* row = lds + (t >> 6) * 128;
    for (int ls = 0; ls <= 6; ++ls) {
        int s = 1 << ls;
        int off = j & (s - 1);
        int i0 = ((j >> ls) << (ls + 1)) + off;
        float ang = PI_F * (float)off / (float)s;
        float sn, cs;
        __sincosf(ang, &sn, &cs);
        float2 a = row[i0];
        float2 bb = row[i0 + s];
        float tx = bb.x * cs - bb.y * sn, ty = bb.x * sn + bb.y * cs;
        row[i0] = make_float2(a.x + tx, a.y + ty);
        row[i0 + s] = make_float2(a.x - tx, a.y - ty);
        __syncthreads();
    }
    unsigned* xo = (unsigned*)xe + (((size_t)img * HWSZ + (size_t)r0 * NW) >> 1) + t;
    xo[0] = pack2(lds[2 * t].x, lds[2 * t + 1].x);
}

// K6: out = x + w_out * x_enh. c-tile 16 (grid 2048), 8 loads in flight, NT out stores.
__global__ void __launch_bounds__(256, 4) out_kernel(const float* __restrict__ x,
                                                     const float* __restrict__ w_out,
                                                     const unsigned short* __restrict__ xe,
                                                     float* __restrict__ out) {
    int b  = blockIdx.z;
    int ct = blockIdx.y;
    int p4 = blockIdx.x * 256 + threadIdx.x;
    const u32x2_t* xeb = (const u32x2_t*)(xe + (size_t)b * CMID * HWSZ);
    f32x4_t e[CMID];
#pragma unroll
    for (int m = 0; m < CMID; ++m) {
        u32x2_t u = xeb[(size_t)m * HW4 + p4];
        e[m] = (f32x4_t){ bf_lo(u.x), bf_hi(u.x), bf_lo(u.y), bf_hi(u.y) };
    }
    const f32x4_t* xb = (const f32x4_t*)(x + (size_t)b * CIN * HWSZ);
    f32x4_t* ob = (f32x4_t*)(out + (size_t)b * CIN * HWSZ);
    int c0 = ct * 16;
    for (int c = c0; c < c0 + 16; c += 8) {
        f32x4_t a[8];
#pragma unroll
        for (int k = 0; k < 8; ++k)
            a[k] = xb[(size_t)(c + k) * HW4 + p4];
#pragma unroll
        for (int m = 0; m < CMID; ++m) {
#pragma unroll
            for (int k = 0; k < 8; ++k)
                a[k] += w_out[(c + k) * CMID + m] * e[m];
        }
#pragma unroll
        for (int k = 0; k < 8; ++k)
            __builtin_nontemporal_store(a[k], ob + (size_t)(c + k) * HW4 + p4);
    }
}

extern "C" void kernel_launch(void* const* d_in, const int* in_sizes, int n_in,
                              void* d_out, int out_size, void* d_ws, size_t ws_size,
                              hipStream_t stream) {
    const float* x     = (const float*)d_in[0];
    const float* w_in  = (const float*)d_in[1];
    const float* w_out = (const float*)d_in[2];
    const float* fw    = (const float*)d_in[3];
    float* out = (float*)d_out;

    int nchunk = 8;
    while (nchunk > 1) {
        size_t need = (size_t)NB * nchunk * CMID * HWSZ * 2   // partials bf16
                    + (size_t)NB * CMID * HWSZ * 4            // xf bf16-complex
                    + (size_t)CMID * HWSZ * 4;                // gain fp32
        if (need <= ws_size) break;
        nchunk >>= 1;
    }
    unsigned short* partials = (unsigned short*)d_ws;
    unsigned* xfu = (unsigned*)(partials + (size_t)NB * nchunk * CMID * HWSZ);
    float*    gain = (float*)(xfu + (size_t)NB * CMID * HWSZ);
    unsigned short* xe = partials;                    // reuse (4 MB <= partials size)

    gain_kernel<<<HWSZ / 256, 256, 0, stream>>>(fw, gain);
    proj_partial<<<dim3(HW4 / 256, nchunk, NB), 256, 0, stream>>>(x, w_in, partials, nchunk);
    reduce_fft_rows<<<dim3(NH / 4, NB * CMID), 256, 0, stream>>>(partials, xfu, nchunk);
    fft_cols_gain<<<dim3(NW / 32, NB * CMID), 256, 0, stream>>>(xfu, gain);
    ifft_rows<<<dim3(NH / 4, NB * CMID), 256, 0, stream>>>(xfu, xe);
    out_kernel<<<dim3(HW4 / 256, CIN / 16, NB), 256, 0, stream>>>(x, w_out, xe, out);
}

// Round 13
// 109.443 us; speedup vs baseline: 1.6800x; 1.0138x over previous
//
#include <hip/hip_runtime.h>
#include <math.h>

#define NB   8
#define CIN  256
#define CMID 16
#define NH   128
#define NW   128
#define HWSZ 16384
#define HW4  4096
#define NANG 8
#define NRAD 9

typedef float    f32x4_t __attribute__((ext_vector_type(4)));
typedef unsigned u32x2_t __attribute__((ext_vector_type(2)));

__device__ __forceinline__ unsigned short f2bf(float f) {
    unsigned u = __float_as_uint(f);
    u += 0x7fffu + ((u >> 16) & 1u);          // round-to-nearest-even
    return (unsigned short)(u >> 16);
}
__device__ __forceinline__ float bf_lo(unsigned u) { return __uint_as_float(u << 16); }
__device__ __forceinline__ float bf_hi(unsigned u) { return __uint_as_float(u & 0xffff0000u); }
__device__ __forceinline__ unsigned pack2(float a, float b) {
    return (unsigned)f2bf(a) | ((unsigned)f2bf(b) << 16);
}

__device__ __forceinline__ int bitrev7(int v) {
    return (int)(__brev((unsigned)v) >> 25);
}

// Gain in bit-reversed (both dims), ifftshift-folded order, pre-scaled by 1/16384.
__global__ void __launch_bounds__(256) gain_kernel(const float* __restrict__ fw,
                                                   float* __restrict__ gain) {
    int p  = blockIdx.x * 256 + threadIdx.x;
    int py = p >> 7, px = p & 127;
    int fy = bitrev7(py), fx = bitrev7(px);
    int hy = (fy + 64) & 127, hx = (fx + 64) & 127;
    float dy = (float)(hy - 64), dx = (float)(hx - 64);
    float r = sqrtf(dy * dy + dx * dx);
    int ridx = (int)floorf(r * 0.125f);
    if (ridx > NRAD - 1) ridx = NRAD - 1;
    const float PI_F = 3.14159265358979323846f;
    float theta = fmodf(atan2f(dy, dx) + PI_F, PI_F);
    const float delta = (float)(M_PI / 8.0);
    const float hwid  = (float)(1.5 * (M_PI / 8.0) / 2.0);
    float wv[NANG];
    float wsum = 0.f;
#pragma unroll
    for (int a = 0; a < NANG; ++a) {
        float c = ((float)a + 0.5f) * delta;
        float dist = fabsf(theta - c);
        float wa = fmaxf(1.0f - dist / hwid, 0.0f);
        if (!(dist < hwid)) wa = 0.0f;
        wv[a] = wa;
        wsum += wa;
    }
    float inv = 1.0f / (wsum + 1e-8f);
#pragma unroll
    for (int m = 0; m < CMID; ++m) {
        float g = 0.f;
#pragma unroll
        for (int a = 0; a < NANG; ++a)
            g += wv[a] * fw[(m * NANG + a) * NRAD + ridx];
        gain[m * HWSZ + p] = g * inv * (1.0f / 16384.0f);
    }
}

// K2: split-K projection, float4 lanes, 8 loads in flight, bf16 partial stores.
__global__ void __launch_bounds__(256, 4) proj_partial(const float* __restrict__ x,
                                                       const float* __restrict__ w_in,
                                                       unsigned short* __restrict__ partials,
                                                       int nchunk) {
    int b  = blockIdx.z;
    int ck = blockIdx.y;
    int p4 = blockIdx.x * 256 + threadIdx.x;          // float4 index, 4096/image
    int cpc = CIN / nchunk;
    int c0 = ck * cpc;
    const f32x4_t* xb = (const f32x4_t*)(x + (size_t)b * CIN * HWSZ);
    f32x4_t acc[CMID];
#pragma unroll
    for (int m = 0; m < CMID; ++m) acc[m] = (f32x4_t){0.f, 0.f, 0.f, 0.f};
    for (int c = c0; c < c0 + cpc; c += 8) {
        f32x4_t v[8];
#pragma unroll
        for (int k = 0; k < 8; ++k)
            v[k] = xb[(size_t)(c + k) * HW4 + p4];
#pragma unroll
        for (int k = 0; k < 8; ++k) {
#pragma unroll
            for (int m = 0; m < CMID; ++m)
                acc[m] += w_in[m * CIN + c + k] * v[k];
        }
    }
    ushort4* pb = (ushort4*)partials + ((size_t)(b * nchunk + ck) * CMID) * HW4;
#pragma unroll
    for (int m = 0; m < CMID; ++m)
        pb[(size_t)m * HW4 + p4] = make_ushort4(f2bf(acc[m].x), f2bf(acc[m].y),
                                                f2bf(acc[m].z), f2bf(acc[m].w));
}

// K3: reduce bf16 partials + forward row-DIF FFT, radix-2^2 (4 barriers).
// Block = 8 rows of one (b,m) image; final s=1 stage (W=1) fused into write.
__global__ void __launch_bounds__(256) reduce_fft_rows(const unsigned short* __restrict__ partials,
                                                       unsigned* __restrict__ xf,
                                                       int nchunk) {
    __shared__ float2 lds[1024];                      // 8 rows x 128, 8 KB
    int img = blockIdx.y;                             // b*16 + m
    int b = img >> 4, m = img & 15;
    int r0 = blockIdx.x * 8;
    int t = threadIdx.x;
    const unsigned* pbase = (const unsigned*)(partials +
        ((size_t)(b * nchunk) * CMID + m) * HWSZ + (size_t)r0 * NW);
    size_t cks = (size_t)CMID * HWSZ / 2;             // uints per chunk
#pragma unroll
    for (int ii = 0; ii < 2; ++ii) {
        int idx = ii * 256 + t;                       // uint index, 512 per strip
        float sx = 0.f, sy = 0.f;
        if (nchunk == 8) {
#pragma unroll
            for (int ck = 0; ck < 8; ++ck) {
                unsigned u = pbase[(size_t)ck * cks + idx];
                sx += bf_lo(u); sy += bf_hi(u);
            }
        } else {
            for (int ck = 0; ck < nchunk; ++ck) {
                unsigned u = pbase[(size_t)ck * cks + idx];
                sx += bf_lo(u); sy += bf_hi(u);
            }
        }
        lds[2 * idx]     = make_float2(sx, 0.f);
        lds[2 * idx + 1] = make_float2(sy, 0.f);
    }
    __syncthreads();
    const float PI_F = 3.14159265358979323846f;
    int row = t >> 5, k = t & 31;
    float2* rb = lds + row * 128;
    for (int sp = 6; sp >= 2; sp -= 2) {
        int s = 1 << sp, h = s >> 1;
        int o = k & (h - 1);
        int i0 = ((k >> (sp - 1)) << (sp + 1)) + o;
        float ang = -PI_F * (float)o / (float)s;
        float sn, cs;
        __sincosf(ang, &sn, &cs);
        float wbc = cs * cs - sn * sn, wbs = 2.f * cs * sn;   // WB = WA^2
        float2 x0 = rb[i0],     x1 = rb[i0 + h];
        float2 x2 = rb[i0 + s], x3 = rb[i0 + s + h];
        float2 y0 = make_float2(x0.x + x2.x, x0.y + x2.y);
        float dx = x0.x - x2.x, dy = x0.y - x2.y;
        float2 y2 = make_float2(dx * cs - dy * sn, dx * sn + dy * cs);
        float2 y1 = make_float2(x1.x + x3.x, x1.y + x3.y);
        dx = x1.x - x3.x; dy = x1.y - x3.y;
        float2 y3 = make_float2(dx * sn + dy * cs, dy * sn - dx * cs);
        float2 z0 = make_float2(y0.x + y1.x, y0.y + y1.y);
        dx = y0.x - y1.x; dy = y0.y - y1.y;
        float2 z1 = make_float2(dx * wbc - dy * wbs, dx * wbs + dy * wbc);
        float2 z2 = make_float2(y2.x + y3.x, y2.y + y3.y);
        dx = y2.x - y3.x; dy = y2.y - y3.y;
        float2 z3 = make_float2(dx * wbc - dy * wbs, dx * wbs + dy * wbc);
        rb[i0] = z0;     rb[i0 + h] = z1;
        rb[i0 + s] = z2; rb[i0 + s + h] = z3;
        __syncthreads();
    }
    // final DIF stage s=1 (W=1) fused into packed write, 8B stores
    u32x2_t* xo = (u32x2_t*)(xf + (size_t)img * HWSZ + (size_t)r0 * NW);
#pragma unroll
    for (int ii = 0; ii < 2; ++ii) {
        int i = ii * 256 + t;                         // pair index, 512 per strip
        float2 a = lds[2 * i], b2 = lds[2 * i + 1];
        xo[i] = (u32x2_t){ pack2(a.x + b2.x, a.y + b2.y),
                           pack2(a.x - b2.x, a.y - b2.y) };
    }
}

// K4: radix-2^2 col FFT + gain + inverse, 8 barrier phases.
__global__ void __launch_bounds__(256) fft_cols_gain(unsigned* __restrict__ xf,
                                                     const float* __restrict__ gain) {
    __shared__ float2 buf[128 * 33];
    int img = blockIdx.y;
    int m   = img & (CMID - 1);
    int c0  = blockIdx.x * 32;
    int t   = threadIdx.x;
    unsigned* xi = xf + (size_t)img * HWSZ;

    for (int idx = t; idx < 4096; idx += 256) {
        int r = idx >> 5, lc = idx & 31;
        unsigned u = xi[r * NW + c0 + lc];
        buf[r * 33 + lc] = make_float2(bf_lo(u), bf_hi(u));
    }
    __syncthreads();
    const float PI_F = 3.14159265358979323846f;
    int lc = t & 31;
    int kb = t >> 5;                              // 0..7
    for (int sp = 6; sp >= 2; sp -= 2) {
        int s = 1 << sp, h = s >> 1;
        for (int k = kb; k < 32; k += 8) {
            int o = k & (h - 1);
            int i0 = ((k >> (sp - 1)) << (sp + 1)) + o;
            float ang = -PI_F * (float)o / (float)s;
            float sn, cs;
            __sincosf(ang, &sn, &cs);
            float wbc = cs * cs - sn * sn, wbs = 2.f * cs * sn;
            float2 x0 = buf[i0 * 33 + lc],       x1 = buf[(i0 + h) * 33 + lc];
            float2 x2 = buf[(i0 + s) * 33 + lc], x3 = buf[(i0 + s + h) * 33 + lc];
            float2 y0 = make_float2(x0.x + x2.x, x0.y + x2.y);
            float dx = x0.x - x2.x, dy = x0.y - x2.y;
            float2 y2 = make_float2(dx * cs - dy * sn, dx * sn + dy * cs);
            float2 y1 = make_float2(x1.x + x3.x, x1.y + x3.y);
            dx = x1.x - x3.x; dy = x1.y - x3.y;
            float2 y3 = make_float2(dx * sn + dy * cs, dy * sn - dx * cs);
            float2 z0 = make_float2(y0.x + y1.x, y0.y + y1.y);
            dx = y0.x - y1.x; dy = y0.y - y1.y;
            float2 z1 = make_float2(dx * wbc - dy * wbs, dx * wbs + dy * wbc);
            float2 z2 = make_float2(y2.x + y3.x, y2.y + y3.y);
            dx = y2.x - y3.x; dy = y2.y - y3.y;
            float2 z3 = make_float2(dx * wbc - dy * wbs, dx * wbs + dy * wbc);
            buf[i0 * 33 + lc] = z0;       buf[(i0 + h) * 33 + lc] = z1;
            buf[(i0 + s) * 33 + lc] = z2; buf[(i0 + s + h) * 33 + lc] = z3;
        }
        __syncthreads();
    }
    {
        const float* gm = gain + (size_t)m * HWSZ + c0;
        for (int idx = t; idx < 2048; idx += 256) {
            int i0 = (idx >> 5) * 2, lc2 = idx & 31;
            float2 a = buf[i0 * 33 + lc2], b = buf[(i0 + 1) * 33 + lc2];
            float g0 = gm[i0 * NW + lc2], g1 = gm[(i0 + 1) * NW + lc2];
            float v0x = (a.x + b.x) * g0, v0y = (a.y + b.y) * g0;
            float v1x = (a.x - b.x) * g1, v1y = (a.y - b.y) * g1;
            buf[i0 * 33 + lc2]       = make_float2(v0x + v1x, v0y + v1y);
            buf[(i0 + 1) * 33 + lc2] = make_float2(v0x - v1x, v0y - v1y);
        }
        __syncthreads();
    }
    for (int sp = 2; sp <= 6; sp += 2) {
        int s = 1 << sp, h = s >> 1;
        for (int k = kb; k < 32; k += 8) {
            int o = k & (h - 1);
            int i0 = ((k >> (sp - 1)) << (sp + 1)) + o;
            float ang = PI_F * (float)o / (float)s;
            float sn, cs;
            __sincosf(ang, &sn, &cs);
            float wbc = cs * cs - sn * sn, wbs = 2.f * cs * sn;
            float2 x0 = buf[i0 * 33 + lc],       x1 = buf[(i0 + h) * 33 + lc];
            float2 x2 = buf[(i0 + s) * 33 + lc], x3 = buf[(i0 + s + h) * 33 + lc];
            float tx = x1.x * wbc - x1.y * wbs, ty = x1.x * wbs + x1.y * wbc;
            float2 y0 = make_float2(x0.x + tx, x0.y + ty);
            float2 y1 = make_float2(x0.x - tx, x0.y - ty);
            tx = x3.x * wbc - x3.y * wbs; ty = x3.x * wbs + x3.y * wbc;
            float2 y2 = make_float2(x2.x + tx, x2.y + ty);
            float2 y3 = make_float2(x2.x - tx, x2.y - ty);
            tx = y2.x * cs - y2.y * sn; ty = y2.x * sn + y2.y * cs;
            float2 z0 = make_float2(y0.x + tx, y0.y + ty);
            float2 z2 = make_float2(y0.x - tx, y0.y - ty);
            tx = -y3.x * sn - y3.y * cs; ty = y3.x * cs - y3.y * sn;
            float2 z1 = make_float2(y1.x + tx, y1.y + ty);
            float2 z3 = make_float2(y1.x - tx, y1.y - ty);
            buf[i0 * 33 + lc] = z0;       buf[(i0 + h) * 33 + lc] = z1;
            buf[(i0 + s) * 33 + lc] = z2; buf[(i0 + s + h) * 33 + lc] = z3;
        }
        __syncthreads();
    }
    for (int idx = t; idx < 4096; idx += 256) {
        int r = idx >> 5, lc2 = idx & 31;
        xi[r * NW + c0 + lc2] = pack2(buf[r * 33 + lc2].x, buf[r * 33 + lc2].y);
    }
}

// K5: inverse row-DIT radix-2^2 (4 barriers); stage s=1 fused into load;
// write real x_enh as bf16. Block = 8 rows of one image.
__global__ void __launch_bounds__(256) ifft_rows(const unsigned* __restrict__ xf,
                                                 unsigned short* __restrict__ xe) {
    __shared__ float2 lds[1024];                      // 8 KB
    int img = blockIdx.y;
    int r0 = blockIdx.x * 8;
    int t = threadIdx.x;
    const unsigned* xi = xf + (size_t)img * HWSZ + (size_t)r0 * NW;
#pragma unroll
    for (int ii = 0; ii < 2; ++ii) {
        int i = ii * 256 + t;                         // pair index, 512 per strip
        unsigned ua = xi[2 * i], ub = xi[2 * i + 1];
        float ax = bf_lo(ua), ay = bf_hi(ua), bx = bf_lo(ub), by = bf_hi(ub);
        lds[2 * i]     = make_float2(ax + bx, ay + by);   // inverse stage s=1 (W=1)
        lds[2 * i + 1] = make_float2(ax - bx, ay - by);
    }
    __syncthreads();
    const float PI_F = 3.14159265358979323846f;
    int row = t >> 5, k = t & 31;
    float2* rb = lds + row * 128;
    for (int sp = 2; sp <= 6; sp += 2) {
        int s = 1 << sp, h = s >> 1;
        int o = k & (h - 1);
        int i0 = ((k >> (sp - 1)) << (sp + 1)) + o;
        float ang = PI_F * (float)o / (float)s;
        float sn, cs;
        __sincosf(ang, &sn, &cs);
        float wbc = cs * cs - sn * sn, wbs = 2.f * cs * sn;
        float2 x0 = rb[i0],     x1 = rb[i0 + h];
        float2 x2 = rb[i0 + s], x3 = rb[i0 + s + h];
        float tx = x1.x * wbc - x1.y * wbs, ty = x1.x * wbs + x1.y * wbc;
        float2 y0 = make_float2(x0.x + tx, x0.y + ty);
        float2 y1 = make_float2(x0.x - tx, x0.y - ty);
        tx = x3.x * wbc - x3.y * wbs; ty = x3.x * wbs + x3.y * wbc;
        float2 y2 = make_float2(x2.x + tx, x2.y + ty);
        float2 y3 = make_float2(x2.x - tx, x2.y - ty);
        tx = y2.x * cs - y2.y * sn; ty = y2.x * sn + y2.y * cs;
        float2 z0 = make_float2(y0.x + tx, y0.y + ty);
        float2 z2 = make_float2(y0.x - tx, y0.y - ty);
        tx = -y3.x * sn - y3.y * cs; ty = y3.x * cs - y3.y * sn;
        float2 z1 = make_float2(y1.x + tx, y1.y + ty);
        float2 z3 = make_float2(y1.x - tx, y1.y - ty);
        rb[i0] = z0;     rb[i0 + h] = z1;
        rb[i0 + s] = z2; rb[i0 + s + h] = z3;
        __syncthreads();
    }
    unsigned* xo = (unsigned*)xe + (((size_t)img * HWSZ + (size_t)r0 * NW) >> 1);
#pragma unroll
    for (int ii = 0; ii < 2; ++ii) {
        int i = ii * 256 + t;                         // uint index = px pair {2i,2i+1}
        xo[i] = pack2(lds[2 * i].x, lds[2 * i + 1].x);
    }
}

// K6: out = x + w_out * x_enh. c-tile 16 (grid 2048), 8 loads in flight, NT out stores.
__global__ void __launch_bounds__(256, 4) out_kernel(const float* __restrict__ x,
                                                     const float* __restrict__ w_out,
                                                     const unsigned short* __restrict__ xe,
                                                     float* __restrict__ out) {
    int b  = blockIdx.z;
    int ct = blockIdx.y;
    int p4 = blockIdx.x * 256 + threadIdx.x;
    const u32x2_t* xeb = (const u32x2_t*)(xe + (size_t)b * CMID * HWSZ);
    f32x4_t e[CMID];
#pragma unroll
    for (int m = 0; m < CMID; ++m) {
        u32x2_t u = xeb[(size_t)m * HW4 + p4];
        e[m] = (f32x4_t){ bf_lo(u.x), bf_hi(u.x), bf_lo(u.y), bf_hi(u.y) };
    }
    const f32x4_t* xb = (const f32x4_t*)(x + (size_t)b * CIN * HWSZ);
    f32x4_t* ob = (f32x4_t*)(out + (size_t)b * CIN * HWSZ);
    int c0 = ct * 16;
    for (int c = c0; c < c0 + 16; c += 8) {
        f32x4_t a[8];
#pragma unroll
        for (int k = 0; k < 8; ++k)
            a[k] = xb[(size_t)(c + k) * HW4 + p4];
#pragma unroll
        for (int m = 0; m < CMID; ++m) {
#pragma unroll
            for (int k = 0; k < 8; ++k)
                a[k] += w_out[(c + k) * CMID + m] * e[m];
        }
#pragma unroll
        for (int k = 0; k < 8; ++k)
            __builtin_nontemporal_store(a[k], ob + (size_t)(c + k) * HW4 + p4);
    }
}

extern "C" void kernel_launch(void* const* d_in, const int* in_sizes, int n_in,
                              void* d_out, int out_size, void* d_ws, size_t ws_size,
                              hipStream_t stream) {
    const float* x     = (const float*)d_in[0];
    const float* w_in  = (const float*)d_in[1];
    const float* w_out = (const float*)d_in[2];
    const float* fw    = (const float*)d_in[3];
    float* out = (float*)d_out;

    int nchunk = 8;
    while (nchunk > 1) {
        size_t need = (size_t)NB * nchunk * CMID * HWSZ * 2   // partials bf16
                    + (size_t)NB * CMID * HWSZ * 4            // xf bf16-complex
                    + (size_t)CMID * HWSZ * 4;                // gain fp32
        if (need <= ws_size) break;
        nchunk >>= 1;
    }
    unsigned short* partials = (unsigned short*)d_ws;
    unsigned* xfu = (unsigned*)(partials + (size_t)NB * nchunk * CMID * HWSZ);
    float*    gain = (float*)(xfu + (size_t)NB * CMID * HWSZ);
    unsigned short* xe = partials;                    // reuse (4 MB <= partials size)

    gain_kernel<<<HWSZ / 256, 256, 0, stream>>>(fw, gain);
    proj_partial<<<dim3(HW4 / 256, nchunk, NB), 256, 0, stream>>>(x, w_in, partials, nchunk);
    reduce_fft_rows<<<dim3(NH / 8, NB * CMID), 256, 0, stream>>>(partials, xfu, nchunk);
    fft_cols_gain<<<dim3(NW / 32, NB * CMID), 256, 0, stream>>>(xfu, gain);
    ifft_rows<<<dim3(NH / 8, NB * CMID), 256, 0, stream>>>(xfu, xe);
    out_kernel<<<dim3(HW4 / 256, CIN / 16, NB), 256, 0, stream>>>(x, w_out, xe, out);
}